// Round 11
// baseline (912.931 us; speedup 1.0000x reference)
//
#include <hip/hip_runtime.h>
#include <hip/hip_fp16.h>
#include <math.h>

#define Q    4096
#define NN   16384
#define DD   256
#define KSEL 33
#define CAND 96    // per-wave candidate cap (>= 33 + exact-f16 ties; r8-validated)
#define OSTR 264   // epilogue LDS row stride bytes: 256 B data + 8 B pad

typedef __attribute__((ext_vector_type(8))) _Float16 half8;
typedef __attribute__((ext_vector_type(4))) float    floatx4;

__device__ __forceinline__ float h2f(unsigned short u) {
    union { unsigned short s; _Float16 h; } c; c.s = u;
    return (float)c.h;
}
// f32 -> f16 raw bits, guaranteed FINITE pattern (exp field != 0x1F)
__device__ __forceinline__ unsigned short f2h_finite(float v) {
    v = fminf(fmaxf(v, -65504.0f), 65504.0f);       // IEEE fmax/fmin: NaN -> -65504
    union { _Float16 h; unsigned short s; } c; c.h = (_Float16)v;
    unsigned short u = c.s;
    if ((u & 0x7C00u) == 0x7C00u) u = (u & 0x8000u) ? 0xFBFFu : 0x7BFFu;
    return u;
}
__device__ __forceinline__ unsigned int patch16(unsigned int u) {
    if ((u & 0x7C00u) == 0x7C00u) u = (u & 0x8000u) ? 0xFBFFu : 0x7BFFu;
    return u;
}
// monotone f16-bits -> sortable u16 (larger float => larger key); involutive pair
__device__ __forceinline__ unsigned int key_of(unsigned int u) {
    return (u & 0x8000u) ? (u ^ 0xFFFFu) : (u | 0x8000u);
}
__device__ __forceinline__ unsigned int inv_key(unsigned int k) {
    return (k & 0x8000u) ? (k ^ 0x8000u) : (~k & 0xFFFFu);
}
// async 16B global -> LDS (m97). Dest = wave-uniform base + lane*16 [m104].
__device__ __forceinline__ void gload_lds16(const unsigned short* g, char* l) {
    __builtin_amdgcn_global_load_lds(
        (const __attribute__((address_space(1))) void*)g,
        (__attribute__((address_space(3))) void*)l, 16, 0, 0);
}

// ---------------------------------------------------------------- row norms -> ws
__global__ __launch_bounds__(256) void norms_kernel(const unsigned short* __restrict__ x,
                                                    const unsigned short* __restrict__ xn,
                                                    float* __restrict__ ws) {
    const int t = threadIdx.x;
    const int g = blockIdx.x * 64 + (t >> 2);
    const int sub = t & 3;
    const unsigned short* src = (g < Q) ? (x + (size_t)g * DD)
                                        : (xn + (size_t)(g - Q) * DD);
    float s = 0.f;
#pragma unroll
    for (int it = 0; it < 8; ++it) {
        const uint4 v = *(const uint4*)(src + (it * 4 + sub) * 8);
        const unsigned int* w = (const unsigned int*)&v;
#pragma unroll
        for (int q = 0; q < 4; ++q) {
            const float a = h2f(w[q] & 0xFFFF), b = h2f(w[q] >> 16);
            s = fmaf(a, a, s); s = fmaf(b, b, s);
        }
    }
    s += __shfl_xor(s, 1);
    s += __shfl_xor(s, 2);
    if (sub == 0) ws[g] = s;
}

// ---------------------------------------------------------------- sim GEMM (MFMA f16)
// XOR-swizzled staging: LDS slot t holds global k-chunk kk=(qq-(r0>>1))&3 of its
// row, so async dest stays contiguous (t*16) while fragment ds_read_b128 banks
// cover all 8 groups exactly twice (2-way = free [m136]) instead of 8-way.
template <bool WS>
__global__ __launch_bounds__(256) void gemm_sim_kernel(const unsigned short* __restrict__ A,
                                                       const unsigned short* __restrict__ B,
                                                       const float* __restrict__ ws,
                                                       unsigned short* __restrict__ out) {
    __shared__ char  lds[128 * OSTR];   // staging 16KB in K-loop; transpose buf in epilogue
    __shared__ float s_x2[128];
    __shared__ float s_y2[128];
    char* ldsA = lds;            // 128 rows x 64B; slot byte offset == t*16 (+ j*4096)
    char* ldsB = lds + 8192;

    const int t    = threadIdx.x;
    const int m0   = blockIdx.y * 128;
    const int n0   = blockIdx.x * 128;
    const int wave = t >> 6;
    const int lane = t & 63;
    const int wm   = (wave & 1) << 6;
    const int wn   = (wave >> 1) << 6;
    const int l15  = lane & 15;
    const int quad = lane >> 4;
    const int r0   = t >> 2;
    const int qq   = t & 3;
    const int kk   = (qq - (r0 >> 1)) & 3;   // swizzled k-chunk this thread stages

    if (WS) {
        if (t < 128) s_x2[t] = ws[m0 + t];
        else         s_y2[t - 128] = ws[Q + n0 + (t - 128)];
    }

    floatx4 acc[4][4];
#pragma unroll
    for (int i = 0; i < 4; ++i)
#pragma unroll
        for (int j = 0; j < 4; ++j) {
            acc[i][j][0] = 0.f; acc[i][j][1] = 0.f; acc[i][j][2] = 0.f; acc[i][j][3] = 0.f;
        }
    float pa[2] = {0.f, 0.f}, pb[2] = {0.f, 0.f};

    for (int k0 = 0; k0 < DD; k0 += 32) {
        if (WS) {
            __syncthreads();     // previous iteration's frag reads done
#pragma unroll
            for (int j = 0; j < 2; ++j) {
                gload_lds16(A + (size_t)(m0 + r0 + 64 * j) * DD + k0 + kk * 8,
                            ldsA + j * 4096 + t * 16);
                gload_lds16(B + (size_t)(n0 + r0 + 64 * j) * DD + k0 + kk * 8,
                            ldsB + j * 4096 + t * 16);
            }
        } else {
            float4 ar[2], br[2];
#pragma unroll
            for (int j = 0; j < 2; ++j) {
                const int r = r0 + (j << 6);
                ar[j] = *(const float4*)(A + (size_t)(m0 + r) * DD + k0 + kk * 8);
                br[j] = *(const float4*)(B + (size_t)(n0 + r) * DD + k0 + kk * 8);
                const unsigned short* ua = (const unsigned short*)&ar[j];
                const unsigned short* ub = (const unsigned short*)&br[j];
#pragma unroll
                for (int e = 0; e < 8; ++e) {
                    const float fa = h2f(ua[e]); pa[j] = fmaf(fa, fa, pa[j]);
                    const float fb = h2f(ub[e]); pb[j] = fmaf(fb, fb, pb[j]);
                }
            }
            __syncthreads();
#pragma unroll
            for (int j = 0; j < 2; ++j) {
                *(float4*)(ldsA + j * 4096 + t * 16) = ar[j];
                *(float4*)(ldsB + j * 4096 + t * 16) = br[j];
            }
        }
        __syncthreads();         // WS: drains vmcnt; !WS: lds writes visible
        half8 af[4], bg[4];
#pragma unroll
        for (int s = 0; s < 4; ++s) {
            const int R = wm + s * 16 + l15;   // A-row (same arithmetic for B)
            const int Rb = wn + s * 16 + l15;
            af[s] = *(const half8*)(ldsA + R  * 64 + ((quad + (R  >> 1)) & 3) * 16);
            bg[s] = *(const half8*)(ldsB + Rb * 64 + ((quad + (Rb >> 1)) & 3) * 16);
        }
#pragma unroll
        for (int si = 0; si < 4; ++si)
#pragma unroll
            for (int sj = 0; sj < 4; ++sj)
                acc[si][sj] = __builtin_amdgcn_mfma_f32_16x16x32_f16(af[si], bg[sj], acc[si][sj], 0, 0, 0);
    }

    if (!WS) {
#pragma unroll
        for (int j = 0; j < 2; ++j) {
            pa[j] += __shfl_xor(pa[j], 1); pa[j] += __shfl_xor(pa[j], 2);
            pb[j] += __shfl_xor(pb[j], 1); pb[j] += __shfl_xor(pb[j], 2);
        }
        if (qq == 0) {
            s_x2[r0] = pa[0]; s_x2[64 + r0] = pa[1];
            s_y2[r0] = pb[0]; s_y2[64 + r0] = pb[1];
        }
    }
    __syncthreads();   // staging reads done -> lds reusable; norms visible

    // epilogue pass 1: acc -> f16 into LDS transpose buffer
    // C/D layout: col = lane&15, row = quad*4 + reg  [m89; dtype-independent]
#pragma unroll
    for (int si = 0; si < 4; ++si) {
#pragma unroll
        for (int r = 0; r < 4; ++r) {
            const int lrow = wm + si * 16 + quad * 4 + r;
            const float xv = s_x2[lrow];
#pragma unroll
            for (int sj = 0; sj < 4; ++sj) {
                const int lcol = wn + sj * 16 + l15;
                float d2 = fmaxf(xv + s_y2[lcol] - 2.0f * acc[si][sj][r], 0.0f);
                d2 = fminf(d2, 1e9f);
                *(unsigned short*)(lds + lrow * OSTR + lcol * 2) = f2h_finite(-sqrtf(d2));
            }
        }
    }
    __syncthreads();

    // epilogue pass 2: coalesced 16B stores
#pragma unroll
    for (int p = 0; p < 8; ++p) {
        const int idx = p * 256 + t;
        const int r = idx >> 4, c = idx & 15;
        *(uint4*)(out + (size_t)(m0 + r) * NN + n0 + c * 8) = *(const uint4*)(lds + r * OSTR + c * 16);
    }
}

// ---------------------------------------------------------------- top-33: per-wave 2-level histogram select + exact merge
// One block per row; thread t owns uint4 chunks j*256+t; gi = 2048j + 8t + e.
// Each wave builds a 256-bin LDS histogram of its 4096 keys' high bytes, finds
// the rank-33 byte B* by suffix-scan, refines on low byte (f16's coarse high
// byte makes bin(B*) large), emits {key >= tau_w}; wave 0 merges exactly.
__global__ __launch_bounds__(256) void topk_kernel(unsigned short* __restrict__ out) {
    const int row = blockIdx.x;
    unsigned short* rowp = out + (size_t)row * NN;
    const int t = threadIdx.x;
    const int lane = t & 63;
    const int wave = t >> 6;

    __shared__ unsigned int s_h1[4][256];
    __shared__ unsigned int s_h2[4][256];
    __shared__ unsigned int s_cand[4][CAND];   // (key<<16) | gi
    __shared__ int          s_cnum[4];
    __shared__ unsigned int s_tau;
    __shared__ int          s_nsel;
    __shared__ int          s_selgi[40];

    // load + transform to sortable keys in-place
    uint4 d[8];
    const uint4* rp4 = (const uint4*)rowp;
#pragma unroll
    for (int j = 0; j < 8; ++j) d[j] = rp4[j * 256 + t];
#pragma unroll
    for (int j = 0; j < 8; ++j) {
        unsigned int* w = (unsigned int*)&d[j];
#pragma unroll
        for (int q = 0; q < 4; ++q)
            w[q] = key_of(w[q] & 0xFFFFu) | (key_of(w[q] >> 16) << 16);
    }

    unsigned int* h1 = s_h1[wave];
    unsigned int* h2 = s_h2[wave];
    // zero both hists (wave-private; same-wave DS ordering guarantees visibility)
#pragma unroll
    for (int q = 0; q < 4; ++q) { h1[q * 64 + lane] = 0u; h2[q * 64 + lane] = 0u; }

    // level-1 histogram: high byte of each key
#pragma unroll
    for (int j = 0; j < 8; ++j) {
        const unsigned int* w = (const unsigned int*)&d[j];
#pragma unroll
        for (int q = 0; q < 4; ++q) {
            atomicAdd(&h1[(w[q] >> 8) & 0xFFu], 1u);
            atomicAdd(&h1[w[q] >> 24], 1u);
        }
    }

    // suffix-scan: lane holds bins {q*64+lane}; sfx = count of keys with byte >= bin
    unsigned int c1[4], sfx1[4];
#pragma unroll
    for (int q = 0; q < 4; ++q) {
        c1[q] = h1[q * 64 + lane];
        unsigned int r = c1[q];
#pragma unroll
        for (int off = 1; off < 64; off <<= 1) {
            const unsigned int v = (unsigned int)__shfl_down((int)r, off);
            r += (lane + off < 64) ? v : 0u;
        }
        sfx1[q] = r;
    }
    const unsigned int S1 = (unsigned int)__shfl((int)sfx1[1], 0);
    const unsigned int S2 = (unsigned int)__shfl((int)sfx1[2], 0);
    const unsigned int S3 = (unsigned int)__shfl((int)sfx1[3], 0);
    const unsigned int above1[4] = {S1 + S2 + S3, S2 + S3, S3, 0u};
    unsigned int best = 0;
#pragma unroll
    for (int q = 0; q < 4; ++q) {
        const unsigned int tot = above1[q] + sfx1[q];     // #keys with high byte >= B
        if (tot >= KSEL) {
            const unsigned int B = (unsigned int)(q * 64 + lane);
            const unsigned int pk = (B << 13) | (tot - c1[q]);   // ngt fits 13 bits (<=4096)
            best = pk > best ? pk : best;
        }
    }
#pragma unroll
    for (int off = 1; off < 64; off <<= 1) {
        const unsigned int o = (unsigned int)__shfl_xor((int)best, off);
        best = o > best ? o : best;
    }
    const unsigned int Bs  = best >> 13;       // rank-33 high byte
    const unsigned int ngt = best & 0x1FFFu;   // #keys with high byte > Bs (< 33)

    // level-2 histogram: low byte among keys with high byte == Bs
#pragma unroll
    for (int j = 0; j < 8; ++j) {
        const unsigned int* w = (const unsigned int*)&d[j];
#pragma unroll
        for (int q = 0; q < 4; ++q) {
            const unsigned int a = w[q] & 0xFFFFu, b = w[q] >> 16;
            if ((a >> 8) == Bs) atomicAdd(&h2[a & 0xFFu], 1u);
            if ((b >> 8) == Bs) atomicAdd(&h2[b & 0xFFu], 1u);
        }
    }
    unsigned int c2[4], sfx2[4];
#pragma unroll
    for (int q = 0; q < 4; ++q) {
        c2[q] = h2[q * 64 + lane];
        unsigned int r = c2[q];
#pragma unroll
        for (int off = 1; off < 64; off <<= 1) {
            const unsigned int v = (unsigned int)__shfl_down((int)r, off);
            r += (lane + off < 64) ? v : 0u;
        }
        sfx2[q] = r;
    }
    const unsigned int T1 = (unsigned int)__shfl((int)sfx2[1], 0);
    const unsigned int T2 = (unsigned int)__shfl((int)sfx2[2], 0);
    const unsigned int T3 = (unsigned int)__shfl((int)sfx2[3], 0);
    const unsigned int above2[4] = {T1 + T2 + T3, T2 + T3, T3, 0u};
    int best2 = -1;
#pragma unroll
    for (int q = 0; q < 4; ++q) {
        if (ngt + above2[q] + sfx2[q] >= KSEL) {
            const int b = q * 64 + lane;
            best2 = b > best2 ? b : best2;
        }
    }
#pragma unroll
    for (int off = 1; off < 64; off <<= 1) {
        const int o = __shfl_xor(best2, off);
        best2 = o > best2 ? o : best2;
    }
    const unsigned int tau = (Bs << 8) | (unsigned int)best2;   // wave rank-33 threshold

    // ---- emit candidates (key >= tau): lane-exclusive-prefix slots (r8 code)
    int cge = 0;
#pragma unroll
    for (int j = 0; j < 8; ++j) {
        const unsigned int* w = (const unsigned int*)&d[j];
#pragma unroll
        for (int q = 0; q < 4; ++q)
            cge += (int)((w[q] & 0xFFFFu) >= tau) + (int)((w[q] >> 16) >= tau);
    }
    int p = cge;
#pragma unroll
    for (int off = 1; off < 64; off <<= 1) {
        const int v = __shfl_up(p, off);
        if (lane >= off) p += v;
    }
    int slot = p - cge;
    if (cge) {
#pragma unroll
        for (int j = 0; j < 8; ++j) {
            const unsigned int* w = (const unsigned int*)&d[j];
#pragma unroll
            for (int q = 0; q < 4; ++q) {
#pragma unroll
                for (int h = 0; h < 2; ++h) {
                    const unsigned int k = h ? (w[q] >> 16) : (w[q] & 0xFFFFu);
                    if (k >= tau) {
                        if (slot < CAND)
                            s_cand[wave][slot] = (k << 16) | (unsigned int)((j << 11) + (t << 3) + q * 2 + h);
                        ++slot;
                    }
                }
            }
        }
    }
    if (lane == 63) s_cnum[wave] = (p < CAND) ? p : CAND;
    __syncthreads();                         // barrier 1

    // ---- wave-0 exact merge of <= 4*CAND candidates (r8 code)
    if (wave == 0) {
        const int n0c = s_cnum[0], n1c = s_cnum[1], n2c = s_cnum[2], n3c = s_cnum[3];
        const int M = n0c + n1c + n2c + n3c;
        unsigned int e[6]; bool val[6];
#pragma unroll
        for (int s = 0; s < 6; ++s) {
            const int i = lane + 64 * s;
            val[s] = (i < M);
            unsigned int v = 0;
            if (val[s]) {
                int ii = i;
                if (ii < n0c) v = s_cand[0][ii];
                else { ii -= n0c;
                    if (ii < n1c) v = s_cand[1][ii];
                    else { ii -= n1c;
                        if (ii < n2c) v = s_cand[2][ii];
                        else v = s_cand[3][ii - n2c]; } }
            }
            e[s] = v;
        }
        unsigned int T = 0;
#pragma unroll
        for (int b = 15; b >= 0; --b) {
            const unsigned int tc = T | (1u << b);
            int c = 0;
#pragma unroll
            for (int s = 0; s < 6; ++s) c += (int)(val[s] && (e[s] >> 16) >= tc);
#pragma unroll
            for (int off = 1; off < 64; off <<= 1) c += __shfl_xor(c, off);
            if (c >= KSEL) T = tc;
        }
        int cgt = 0;
#pragma unroll
        for (int s = 0; s < 6; ++s) cgt += (int)(val[s] && (e[s] >> 16) > T);
#pragma unroll
        for (int off = 1; off < 64; off <<= 1) cgt += __shfl_xor(cgt, off);
        int tneed = KSEL - cgt;
        if (tneed < 0) tneed = 0;
        if (tneed > 40) tneed = 40;

        bool taken[6] = {false, false, false, false, false, false};
        for (int k = 0; k < tneed; ++k) {
            int m = 0x7fffffff;
#pragma unroll
            for (int s = 0; s < 6; ++s)
                if (val[s] && !taken[s] && (e[s] >> 16) == T) {
                    const int g = (int)(e[s] & 0xFFFFu);
                    if (g < m) m = g;
                }
#pragma unroll
            for (int off = 1; off < 64; off <<= 1) {
                const int o = __shfl_xor(m, off);
                if (o < m) m = o;
            }
            if (m == 0x7fffffff) { if (lane == 0) s_selgi[k] = -1; continue; }
#pragma unroll
            for (int s = 0; s < 6; ++s)
                if (val[s] && !taken[s] && (e[s] >> 16) == T && (int)(e[s] & 0xFFFFu) == m) {
                    taken[s] = true;          // unique gi -> exactly one lane
                    s_selgi[k] = m;
                }
        }
        if (lane == 0) { s_tau = T; s_nsel = tneed; }
    }
    __syncthreads();                         // barrier 2

    // ---- predicated writeback: fill 0xFBFF, keep selected (patched-finite)
    const unsigned int T = s_tau;
    const int nsel = s_nsel;
    unsigned long long cons = 0ull;
    for (int k = 0; k < nsel; ++k) {
        const int g = s_selgi[k];
        if (g >= 0 && ((g >> 3) & 255) == t) cons |= 1ull << (((g >> 11) << 3) | (g & 7));
    }
    uint4* wp4 = (uint4*)rowp;
#pragma unroll
    for (int j = 0; j < 8; ++j) {
        const unsigned int* w = (const unsigned int*)&d[j];
        uint4 o;
        unsigned int* ow = (unsigned int*)&o;
#pragma unroll
        for (int q = 0; q < 4; ++q) {
            const unsigned int klo = w[q] & 0xFFFFu, khi = w[q] >> 16;
            const int ord = j * 8 + q * 2;
            const bool sl = (klo > T) || ((cons >> ord) & 1ull);
            const bool sh = (khi > T) || ((cons >> (ord + 1)) & 1ull);
            const unsigned int lo = sl ? patch16(inv_key(klo)) : 0xFBFFu;
            const unsigned int hi = sh ? patch16(inv_key(khi)) : 0xFBFFu;
            ow[q] = lo | (hi << 16);
        }
        wp4[j * 256 + t] = o;
    }
}

// ---------------------------------------------------------------- launch
extern "C" void kernel_launch(void* const* d_in, const int* in_sizes, int n_in,
                              void* d_out, int out_size, void* d_ws, size_t ws_size,
                              hipStream_t stream) {
    const unsigned short* x  = (const unsigned short*)d_in[0];   // [4096 x 256] f16
    const unsigned short* xn = (const unsigned short*)d_in[1];   // [16384 x 256] f16
    unsigned short* out = (unsigned short*)d_out;                // [4096 x 16384] f16
    float* ws = (float*)d_ws;

    const bool use_ws = ws_size >= (size_t)(Q + NN) * sizeof(float);
    if (use_ws) {
        norms_kernel<<<(Q + NN) / 64, 256, 0, stream>>>(x, xn, ws);
        gemm_sim_kernel<true><<<dim3(NN / 128, Q / 128), 256, 0, stream>>>(x, xn, ws, out);
    } else {
        gemm_sim_kernel<false><<<dim3(NN / 128, Q / 128), 256, 0, stream>>>(x, xn, nullptr, out);
    }
    topk_kernel<<<Q, 256, 0, stream>>>(out);
}

// Round 12
// 522.904 us; speedup vs baseline: 1.7459x; 1.7459x over previous
//
#include <hip/hip_runtime.h>
#include <hip/hip_fp16.h>
#include <math.h>

#define Q    4096
#define NN   16384
#define DD   256
#define KSEL 33
#define CAND 96    // per-wave candidate cap (E[cand/wave] ~ 10-25 with tau_lb)
#define OSTR 264   // epilogue LDS row stride bytes: 256 B data + 8 B pad

typedef __attribute__((ext_vector_type(8))) _Float16 half8;
typedef __attribute__((ext_vector_type(4))) float    floatx4;

__device__ __forceinline__ float h2f(unsigned short u) {
    union { unsigned short s; _Float16 h; } c; c.s = u;
    return (float)c.h;
}
// f32 -> f16 raw bits, guaranteed FINITE pattern (exp field != 0x1F)
__device__ __forceinline__ unsigned short f2h_finite(float v) {
    v = fminf(fmaxf(v, -65504.0f), 65504.0f);       // IEEE fmax/fmin: NaN -> -65504
    union { _Float16 h; unsigned short s; } c; c.h = (_Float16)v;
    unsigned short u = c.s;
    if ((u & 0x7C00u) == 0x7C00u) u = (u & 0x8000u) ? 0xFBFFu : 0x7BFFu;
    return u;
}
__device__ __forceinline__ unsigned int patch16(unsigned int u) {
    if ((u & 0x7C00u) == 0x7C00u) u = (u & 0x8000u) ? 0xFBFFu : 0x7BFFu;
    return u;
}
// monotone f16-bits -> sortable u16 (larger float => larger key); involutive pair
__device__ __forceinline__ unsigned int key_of(unsigned int u) {
    return (u & 0x8000u) ? (u ^ 0xFFFFu) : (u | 0x8000u);
}
__device__ __forceinline__ unsigned int inv_key(unsigned int k) {
    return (k & 0x8000u) ? (k ^ 0x8000u) : (~k & 0xFFFFu);
}
// async 16B global -> LDS (m97). Dest = wave-uniform base + lane*16 [m104].
__device__ __forceinline__ void gload_lds16(const unsigned short* g, char* l) {
    __builtin_amdgcn_global_load_lds(
        (const __attribute__((address_space(1))) void*)g,
        (__attribute__((address_space(3))) void*)l, 16, 0, 0);
}

// ---------------------------------------------------------------- row norms -> ws
__global__ __launch_bounds__(256) void norms_kernel(const unsigned short* __restrict__ x,
                                                    const unsigned short* __restrict__ xn,
                                                    float* __restrict__ ws) {
    const int t = threadIdx.x;
    const int g = blockIdx.x * 64 + (t >> 2);
    const int sub = t & 3;
    const unsigned short* src = (g < Q) ? (x + (size_t)g * DD)
                                        : (xn + (size_t)(g - Q) * DD);
    float s = 0.f;
#pragma unroll
    for (int it = 0; it < 8; ++it) {
        const uint4 v = *(const uint4*)(src + (it * 4 + sub) * 8);
        const unsigned int* w = (const unsigned int*)&v;
#pragma unroll
        for (int q = 0; q < 4; ++q) {
            const float a = h2f(w[q] & 0xFFFF), b = h2f(w[q] >> 16);
            s = fmaf(a, a, s); s = fmaf(b, b, s);
        }
    }
    s += __shfl_xor(s, 1);
    s += __shfl_xor(s, 2);
    if (sub == 0) ws[g] = s;
}

// ---------------------------------------------------------------- sim GEMM (MFMA f16) — r10 verbatim (banked)
template <bool WS>
__global__ __launch_bounds__(256) void gemm_sim_kernel(const unsigned short* __restrict__ A,
                                                       const unsigned short* __restrict__ B,
                                                       const float* __restrict__ ws,
                                                       unsigned short* __restrict__ out) {
    __shared__ char  lds[128 * OSTR];   // staging 16KB in K-loop; transpose buf in epilogue
    __shared__ float s_x2[128];
    __shared__ float s_y2[128];
    char* ldsA = lds;            // 128 rows x 64B, offset = row*64 + qq*16 == t*16
    char* ldsB = lds + 8192;

    const int t    = threadIdx.x;
    const int m0   = blockIdx.y * 128;
    const int n0   = blockIdx.x * 128;
    const int wave = t >> 6;
    const int lane = t & 63;
    const int wm   = (wave & 1) << 6;
    const int wn   = (wave >> 1) << 6;
    const int l15  = lane & 15;
    const int quad = lane >> 4;
    const int r0   = t >> 2;
    const int qq   = t & 3;

    if (WS) {
        if (t < 128) s_x2[t] = ws[m0 + t];
        else         s_y2[t - 128] = ws[Q + n0 + (t - 128)];
    }

    floatx4 acc[4][4];
#pragma unroll
    for (int i = 0; i < 4; ++i)
#pragma unroll
        for (int j = 0; j < 4; ++j) {
            acc[i][j][0] = 0.f; acc[i][j][1] = 0.f; acc[i][j][2] = 0.f; acc[i][j][3] = 0.f;
        }
    float pa[2] = {0.f, 0.f}, pb[2] = {0.f, 0.f};

    for (int k0 = 0; k0 < DD; k0 += 32) {
        if (WS) {
            __syncthreads();     // previous iteration's frag reads done
#pragma unroll
            for (int j = 0; j < 2; ++j) {
                gload_lds16(A + (size_t)(m0 + r0 + 64 * j) * DD + k0 + qq * 8,
                            ldsA + j * 4096 + t * 16);
                gload_lds16(B + (size_t)(n0 + r0 + 64 * j) * DD + k0 + qq * 8,
                            ldsB + j * 4096 + t * 16);
            }
        } else {
            float4 ar[2], br[2];
#pragma unroll
            for (int j = 0; j < 2; ++j) {
                const int r = r0 + (j << 6);
                ar[j] = *(const float4*)(A + (size_t)(m0 + r) * DD + k0 + qq * 8);
                br[j] = *(const float4*)(B + (size_t)(n0 + r) * DD + k0 + qq * 8);
                const unsigned short* ua = (const unsigned short*)&ar[j];
                const unsigned short* ub = (const unsigned short*)&br[j];
#pragma unroll
                for (int e = 0; e < 8; ++e) {
                    const float fa = h2f(ua[e]); pa[j] = fmaf(fa, fa, pa[j]);
                    const float fb = h2f(ub[e]); pb[j] = fmaf(fb, fb, pb[j]);
                }
            }
            __syncthreads();
#pragma unroll
            for (int j = 0; j < 2; ++j) {
                const int r = r0 + (j << 6);
                *(float4*)(ldsA + r * 64 + qq * 16) = ar[j];
                *(float4*)(ldsB + r * 64 + qq * 16) = br[j];
            }
        }
        __syncthreads();         // WS: drains vmcnt; !WS: lds writes visible
        half8 af[4], bg[4];
#pragma unroll
        for (int s = 0; s < 4; ++s) {
            af[s] = *(const half8*)(ldsA + (wm + s * 16 + l15) * 64 + quad * 16);
            bg[s] = *(const half8*)(ldsB + (wn + s * 16 + l15) * 64 + quad * 16);
        }
#pragma unroll
        for (int si = 0; si < 4; ++si)
#pragma unroll
            for (int sj = 0; sj < 4; ++sj)
                acc[si][sj] = __builtin_amdgcn_mfma_f32_16x16x32_f16(af[si], bg[sj], acc[si][sj], 0, 0, 0);
    }

    if (!WS) {
#pragma unroll
        for (int j = 0; j < 2; ++j) {
            pa[j] += __shfl_xor(pa[j], 1); pa[j] += __shfl_xor(pa[j], 2);
            pb[j] += __shfl_xor(pb[j], 1); pb[j] += __shfl_xor(pb[j], 2);
        }
        if (qq == 0) {
            s_x2[r0] = pa[0]; s_x2[64 + r0] = pa[1];
            s_y2[r0] = pb[0]; s_y2[64 + r0] = pb[1];
        }
    }
    __syncthreads();   // staging reads done -> lds reusable; norms visible

    // epilogue pass 1: acc -> f16 into LDS transpose buffer
    // C/D layout: col = lane&15, row = quad*4 + reg  [m89; dtype-independent]
#pragma unroll
    for (int si = 0; si < 4; ++si) {
#pragma unroll
        for (int r = 0; r < 4; ++r) {
            const int lrow = wm + si * 16 + quad * 4 + r;
            const float xv = s_x2[lrow];
#pragma unroll
            for (int sj = 0; sj < 4; ++sj) {
                const int lcol = wn + sj * 16 + l15;
                float d2 = fmaxf(xv + s_y2[lcol] - 2.0f * acc[si][sj][r], 0.0f);
                d2 = fminf(d2, 1e9f);
                *(unsigned short*)(lds + lrow * OSTR + lcol * 2) = f2h_finite(-sqrtf(d2));
            }
        }
    }
    __syncthreads();

    // epilogue pass 2: coalesced 16B stores
#pragma unroll
    for (int p = 0; p < 8; ++p) {
        const int idx = p * 256 + t;
        const int r = idx >> 4, c = idx & 15;
        *(uint4*)(out + (size_t)(m0 + r) * NN + n0 + c * 8) = *(const uint4*)(lds + r * OSTR + c * 16);
    }
}

// ---------------------------------------------------------------- top-33: distributed tau_lb prefilter + exact merge
// One block per row; thread t owns uint4 chunks j*256+t; gi = 2048j + 8t + e.
// Per-thread max -> s_tmax. EVERY wave redundantly computes tau_lb = rank-33 of
// the 256 maxima (16-step search over 4 regs: cheap, all waves busy — the r9
// failure was centralizing this on wave 0). tau_lb <= tau* (33 distinct
// thread-maxima >= tau_lb are 33 distinct elements), so {key >= tau_lb}
// contains the exact top-33 incl. ties; E|cand| ~ 40-80/block. Emit + r8's
// validated wave-0 exact merge + predicated writeback.
__global__ __launch_bounds__(256) void topk_kernel(unsigned short* __restrict__ out) {
    const int row = blockIdx.x;
    unsigned short* rowp = out + (size_t)row * NN;
    const int t = threadIdx.x;
    const int lane = t & 63;
    const int wave = t >> 6;

    __shared__ unsigned short s_tmax[256];
    __shared__ unsigned int   s_cand[4][CAND];   // (key<<16) | gi
    __shared__ int            s_cnum[4];
    __shared__ unsigned int   s_tau;
    __shared__ int            s_nsel;
    __shared__ int            s_selgi[40];

    // load + transform to sortable keys in-place
    uint4 d[8];
    const uint4* rp4 = (const uint4*)rowp;
#pragma unroll
    for (int j = 0; j < 8; ++j) d[j] = rp4[j * 256 + t];
#pragma unroll
    for (int j = 0; j < 8; ++j) {
        unsigned int* w = (unsigned int*)&d[j];
#pragma unroll
        for (int q = 0; q < 4; ++q)
            w[q] = key_of(w[q] & 0xFFFFu) | (key_of(w[q] >> 16) << 16);
    }

    // per-thread max of 64 keys (single flat pass)
    unsigned int tm = 0;
#pragma unroll
    for (int j = 0; j < 8; ++j) {
        const unsigned int* w = (const unsigned int*)&d[j];
#pragma unroll
        for (int q = 0; q < 4; ++q) {
            const unsigned int a = w[q] & 0xFFFFu, b = w[q] >> 16;
            const unsigned int m = a > b ? a : b;
            tm = m > tm ? m : tm;
        }
    }
    s_tmax[t] = (unsigned short)tm;
    __syncthreads();                         // barrier 1

    // ALL waves: rank-KSEL threshold over the 256 maxima (redundant, distributed)
    unsigned int k0 = s_tmax[lane],       k1 = s_tmax[lane + 64],
                 k2 = s_tmax[lane + 128], k3 = s_tmax[lane + 192];
    unsigned int taulb = 0;
#pragma unroll
    for (int b = 15; b >= 0; --b) {
        const unsigned int tc = taulb | (1u << b);
        int c = (int)(k0 >= tc) + (int)(k1 >= tc) + (int)(k2 >= tc) + (int)(k3 >= tc);
#pragma unroll
        for (int off = 1; off < 64; off <<= 1) c += __shfl_xor(c, off);
        if (c >= KSEL) taulb = tc;           // wave-uniform
    }

    // emit candidates (key >= taulb): count pass + lane-exclusive-prefix scatter
    int cge = 0;
#pragma unroll
    for (int j = 0; j < 8; ++j) {
        const unsigned int* w = (const unsigned int*)&d[j];
#pragma unroll
        for (int q = 0; q < 4; ++q)
            cge += (int)((w[q] & 0xFFFFu) >= taulb) + (int)((w[q] >> 16) >= taulb);
    }
    int p = cge;
#pragma unroll
    for (int off = 1; off < 64; off <<= 1) {
        const int v = __shfl_up(p, off);
        if (lane >= off) p += v;
    }
    int slot = p - cge;
    if (cge) {                               // most threads have no candidates
#pragma unroll
        for (int j = 0; j < 8; ++j) {
            const unsigned int* w = (const unsigned int*)&d[j];
#pragma unroll
            for (int q = 0; q < 4; ++q) {
#pragma unroll
                for (int h = 0; h < 2; ++h) {
                    const unsigned int k = h ? (w[q] >> 16) : (w[q] & 0xFFFFu);
                    if (k >= taulb) {
                        if (slot < CAND)
                            s_cand[wave][slot] = (k << 16) | (unsigned int)((j << 11) + (t << 3) + q * 2 + h);
                        ++slot;
                    }
                }
            }
        }
    }
    if (lane == 63) s_cnum[wave] = (p < CAND) ? p : CAND;
    __syncthreads();                         // barrier 2

    // wave-0 exact merge of <= 4*CAND candidates (r8-validated code)
    if (wave == 0) {
        const int n0c = s_cnum[0], n1c = s_cnum[1], n2c = s_cnum[2], n3c = s_cnum[3];
        const int M = n0c + n1c + n2c + n3c;
        unsigned int e[6]; bool val[6];
#pragma unroll
        for (int s = 0; s < 6; ++s) {
            const int i = lane + 64 * s;
            val[s] = (i < M);
            unsigned int v = 0;
            if (val[s]) {
                int ii = i;
                if (ii < n0c) v = s_cand[0][ii];
                else { ii -= n0c;
                    if (ii < n1c) v = s_cand[1][ii];
                    else { ii -= n1c;
                        if (ii < n2c) v = s_cand[2][ii];
                        else v = s_cand[3][ii - n2c]; } }
            }
            e[s] = v;
        }
        unsigned int T = 0;
#pragma unroll
        for (int b = 15; b >= 0; --b) {
            const unsigned int tc = T | (1u << b);
            int c = 0;
#pragma unroll
            for (int s = 0; s < 6; ++s) c += (int)(val[s] && (e[s] >> 16) >= tc);
#pragma unroll
            for (int off = 1; off < 64; off <<= 1) c += __shfl_xor(c, off);
            if (c >= KSEL) T = tc;
        }
        int cgt = 0;
#pragma unroll
        for (int s = 0; s < 6; ++s) cgt += (int)(val[s] && (e[s] >> 16) > T);
#pragma unroll
        for (int off = 1; off < 64; off <<= 1) cgt += __shfl_xor(cgt, off);
        int tneed = KSEL - cgt;
        if (tneed < 0) tneed = 0;
        if (tneed > 40) tneed = 40;

        // extract tneed lowest-gi ties (key == T) via iterative butterfly-min
        bool taken[6] = {false, false, false, false, false, false};
        for (int k = 0; k < tneed; ++k) {
            int m = 0x7fffffff;
#pragma unroll
            for (int s = 0; s < 6; ++s)
                if (val[s] && !taken[s] && (e[s] >> 16) == T) {
                    const int g = (int)(e[s] & 0xFFFFu);
                    if (g < m) m = g;
                }
#pragma unroll
            for (int off = 1; off < 64; off <<= 1) {
                const int o = __shfl_xor(m, off);
                if (o < m) m = o;
            }
            if (m == 0x7fffffff) { if (lane == 0) s_selgi[k] = -1; continue; }
#pragma unroll
            for (int s = 0; s < 6; ++s)
                if (val[s] && !taken[s] && (e[s] >> 16) == T && (int)(e[s] & 0xFFFFu) == m) {
                    taken[s] = true;          // unique gi -> exactly one lane
                    s_selgi[k] = m;
                }
        }
        if (lane == 0) { s_tau = T; s_nsel = tneed; }
    }
    __syncthreads();                         // barrier 3

    // predicated writeback: fill 0xFBFF, keep selected (patched-finite)
    const unsigned int T = s_tau;
    const int nsel = s_nsel;
    unsigned long long cons = 0ull;
    for (int k = 0; k < nsel; ++k) {
        const int g = s_selgi[k];
        if (g >= 0 && ((g >> 3) & 255) == t) cons |= 1ull << (((g >> 11) << 3) | (g & 7));
    }
    uint4* wp4 = (uint4*)rowp;
#pragma unroll
    for (int j = 0; j < 8; ++j) {
        const unsigned int* w = (const unsigned int*)&d[j];
        uint4 o;
        unsigned int* ow = (unsigned int*)&o;
#pragma unroll
        for (int q = 0; q < 4; ++q) {
            const unsigned int klo = w[q] & 0xFFFFu, khi = w[q] >> 16;
            const int ord = j * 8 + q * 2;
            const bool sl = (klo > T) || ((cons >> ord) & 1ull);
            const bool sh = (khi > T) || ((cons >> (ord + 1)) & 1ull);
            const unsigned int lo = sl ? patch16(inv_key(klo)) : 0xFBFFu;
            const unsigned int hi = sh ? patch16(inv_key(khi)) : 0xFBFFu;
            ow[q] = lo | (hi << 16);
        }
        wp4[j * 256 + t] = o;
    }
}

// ---------------------------------------------------------------- launch
extern "C" void kernel_launch(void* const* d_in, const int* in_sizes, int n_in,
                              void* d_out, int out_size, void* d_ws, size_t ws_size,
                              hipStream_t stream) {
    const unsigned short* x  = (const unsigned short*)d_in[0];   // [4096 x 256] f16
    const unsigned short* xn = (const unsigned short*)d_in[1];   // [16384 x 256] f16
    unsigned short* out = (unsigned short*)d_out;                // [4096 x 16384] f16
    float* ws = (float*)d_ws;

    const bool use_ws = ws_size >= (size_t)(Q + NN) * sizeof(float);
    if (use_ws) {
        norms_kernel<<<(Q + NN) / 64, 256, 0, stream>>>(x, xn, ws);
        gemm_sim_kernel<true><<<dim3(NN / 128, Q / 128), 256, 0, stream>>>(x, xn, ws, out);
    } else {
        gemm_sim_kernel<false><<<dim3(NN / 128, Q / 128), 256, 0, stream>>>(x, xn, nullptr, out);
    }
    topk_kernel<<<Q, 256, 0, stream>>>(out);
}

// Round 13
// 419.436 us; speedup vs baseline: 2.1766x; 1.2467x over previous
//
#include <hip/hip_runtime.h>
#include <hip/hip_fp16.h>
#include <math.h>

#define Q    4096
#define NN   16384
#define DD   256
#define KSEL 33
#define CAND 96    // per-wave candidate cap (E[cand/wave] ~ 10-25)
#define OSTR 264   // epilogue LDS row stride bytes: 256 B data + 8 B pad
#define TM_BYTES (128 * Q * 2)                 // tilemax[tileN][row] u16 keys
#define WS_NORMS ((size_t)(Q + NN) * 4)
#define WS_FULL  (WS_NORMS + TM_BYTES)

typedef __attribute__((ext_vector_type(8))) _Float16 half8;
typedef __attribute__((ext_vector_type(4))) float    floatx4;

__device__ __forceinline__ float h2f(unsigned short u) {
    union { unsigned short s; _Float16 h; } c; c.s = u;
    return (float)c.h;
}
// f32 -> f16 raw bits, guaranteed FINITE pattern (exp field != 0x1F)
__device__ __forceinline__ unsigned short f2h_finite(float v) {
    v = fminf(fmaxf(v, -65504.0f), 65504.0f);       // IEEE fmax/fmin: NaN -> -65504
    union { _Float16 h; unsigned short s; } c; c.h = (_Float16)v;
    unsigned short u = c.s;
    if ((u & 0x7C00u) == 0x7C00u) u = (u & 0x8000u) ? 0xFBFFu : 0x7BFFu;
    return u;
}
__device__ __forceinline__ unsigned int patch16(unsigned int u) {
    if ((u & 0x7C00u) == 0x7C00u) u = (u & 0x8000u) ? 0xFBFFu : 0x7BFFu;
    return u;
}
// monotone f16-bits -> sortable u16 (larger float => larger key); involutive pair
__device__ __forceinline__ unsigned int key_of(unsigned int u) {
    return (u & 0x8000u) ? (u ^ 0xFFFFu) : (u | 0x8000u);
}
__device__ __forceinline__ unsigned int inv_key(unsigned int k) {
    return (k & 0x8000u) ? (k ^ 0x8000u) : (~k & 0xFFFFu);
}
// async 16B global -> LDS (m97). Dest = wave-uniform base + lane*16 [m104].
__device__ __forceinline__ void gload_lds16(const unsigned short* g, char* l) {
    __builtin_amdgcn_global_load_lds(
        (const __attribute__((address_space(1))) void*)g,
        (__attribute__((address_space(3))) void*)l, 16, 0, 0);
}

// ---------------------------------------------------------------- row norms -> ws
__global__ __launch_bounds__(256) void norms_kernel(const unsigned short* __restrict__ x,
                                                    const unsigned short* __restrict__ xn,
                                                    float* __restrict__ ws) {
    const int t = threadIdx.x;
    const int g = blockIdx.x * 64 + (t >> 2);
    const int sub = t & 3;
    const unsigned short* src = (g < Q) ? (x + (size_t)g * DD)
                                        : (xn + (size_t)(g - Q) * DD);
    float s = 0.f;
#pragma unroll
    for (int it = 0; it < 8; ++it) {
        const uint4 v = *(const uint4*)(src + (it * 4 + sub) * 8);
        const unsigned int* w = (const unsigned int*)&v;
#pragma unroll
        for (int q = 0; q < 4; ++q) {
            const float a = h2f(w[q] & 0xFFFF), b = h2f(w[q] >> 16);
            s = fmaf(a, a, s); s = fmaf(b, b, s);
        }
    }
    s += __shfl_xor(s, 1);
    s += __shfl_xor(s, 2);
    if (sub == 0) ws[g] = s;
}

// ---------------------------------------------------------------- sim GEMM (MFMA f16)
// TM: also emit per-(row, 128-col-tile) max sim as sortable u16 key into tmax
// (f16 rounding is monotone => LDS-f16 maxes equal max of stored values).
template <bool WS, bool TM>
__global__ __launch_bounds__(256) void gemm_sim_kernel(const unsigned short* __restrict__ A,
                                                       const unsigned short* __restrict__ B,
                                                       const float* __restrict__ ws,
                                                       unsigned short* __restrict__ tmax,
                                                       unsigned short* __restrict__ out) {
    __shared__ char  lds[128 * OSTR];   // staging 16KB in K-loop; transpose buf in epilogue
    __shared__ float s_x2[128];
    __shared__ float s_y2[128];
    char* ldsA = lds;            // 128 rows x 64B, offset = row*64 + qq*16 == t*16
    char* ldsB = lds + 8192;

    const int t    = threadIdx.x;
    const int m0   = blockIdx.y * 128;
    const int n0   = blockIdx.x * 128;
    const int wave = t >> 6;
    const int lane = t & 63;
    const int wm   = (wave & 1) << 6;
    const int wn   = (wave >> 1) << 6;
    const int l15  = lane & 15;
    const int quad = lane >> 4;
    const int r0   = t >> 2;
    const int qq   = t & 3;

    if (WS) {
        if (t < 128) s_x2[t] = ws[m0 + t];
        else         s_y2[t - 128] = ws[Q + n0 + (t - 128)];
    }

    floatx4 acc[4][4];
#pragma unroll
    for (int i = 0; i < 4; ++i)
#pragma unroll
        for (int j = 0; j < 4; ++j) {
            acc[i][j][0] = 0.f; acc[i][j][1] = 0.f; acc[i][j][2] = 0.f; acc[i][j][3] = 0.f;
        }
    float pa[2] = {0.f, 0.f}, pb[2] = {0.f, 0.f};

    for (int k0 = 0; k0 < DD; k0 += 32) {
        if (WS) {
            __syncthreads();     // previous iteration's frag reads done
#pragma unroll
            for (int j = 0; j < 2; ++j) {
                gload_lds16(A + (size_t)(m0 + r0 + 64 * j) * DD + k0 + qq * 8,
                            ldsA + j * 4096 + t * 16);
                gload_lds16(B + (size_t)(n0 + r0 + 64 * j) * DD + k0 + qq * 8,
                            ldsB + j * 4096 + t * 16);
            }
        } else {
            float4 ar[2], br[2];
#pragma unroll
            for (int j = 0; j < 2; ++j) {
                const int r = r0 + (j << 6);
                ar[j] = *(const float4*)(A + (size_t)(m0 + r) * DD + k0 + qq * 8);
                br[j] = *(const float4*)(B + (size_t)(n0 + r) * DD + k0 + qq * 8);
                const unsigned short* ua = (const unsigned short*)&ar[j];
                const unsigned short* ub = (const unsigned short*)&br[j];
#pragma unroll
                for (int e = 0; e < 8; ++e) {
                    const float fa = h2f(ua[e]); pa[j] = fmaf(fa, fa, pa[j]);
                    const float fb = h2f(ub[e]); pb[j] = fmaf(fb, fb, pb[j]);
                }
            }
            __syncthreads();
#pragma unroll
            for (int j = 0; j < 2; ++j) {
                const int r = r0 + (j << 6);
                *(float4*)(ldsA + r * 64 + qq * 16) = ar[j];
                *(float4*)(ldsB + r * 64 + qq * 16) = br[j];
            }
        }
        __syncthreads();         // WS: drains vmcnt; !WS: lds writes visible
        half8 af[4], bg[4];
#pragma unroll
        for (int s = 0; s < 4; ++s) {
            af[s] = *(const half8*)(ldsA + (wm + s * 16 + l15) * 64 + quad * 16);
            bg[s] = *(const half8*)(ldsB + (wn + s * 16 + l15) * 64 + quad * 16);
        }
#pragma unroll
        for (int si = 0; si < 4; ++si)
#pragma unroll
            for (int sj = 0; sj < 4; ++sj)
                acc[si][sj] = __builtin_amdgcn_mfma_f32_16x16x32_f16(af[si], bg[sj], acc[si][sj], 0, 0, 0);
    }

    if (!WS) {
#pragma unroll
        for (int j = 0; j < 2; ++j) {
            pa[j] += __shfl_xor(pa[j], 1); pa[j] += __shfl_xor(pa[j], 2);
            pb[j] += __shfl_xor(pb[j], 1); pb[j] += __shfl_xor(pb[j], 2);
        }
        if (qq == 0) {
            s_x2[r0] = pa[0]; s_x2[64 + r0] = pa[1];
            s_y2[r0] = pb[0]; s_y2[64 + r0] = pb[1];
        }
    }
    __syncthreads();   // staging reads done -> lds reusable; norms visible

    // epilogue pass 1: acc -> f16 into LDS transpose buffer
    // C/D layout: col = lane&15, row = quad*4 + reg  [m89; dtype-independent]
#pragma unroll
    for (int si = 0; si < 4; ++si) {
#pragma unroll
        for (int r = 0; r < 4; ++r) {
            const int lrow = wm + si * 16 + quad * 4 + r;
            const float xv = s_x2[lrow];
#pragma unroll
            for (int sj = 0; sj < 4; ++sj) {
                const int lcol = wn + sj * 16 + l15;
                float d2 = fmaxf(xv + s_y2[lcol] - 2.0f * acc[si][sj][r], 0.0f);
                d2 = fminf(d2, 1e9f);
                *(unsigned short*)(lds + lrow * OSTR + lcol * 2) = f2h_finite(-sqrtf(d2));
            }
        }
    }
    __syncthreads();

    // tilemax: thread pair (2r, 2r+1) scans LDS row r halves, combines via shfl
    if (TM) {
        const int r = t >> 1, h = t & 1;
        unsigned int mk = 0;
#pragma unroll
        for (int c8 = 0; c8 < 8; ++c8) {
            const uint4 v = *(const uint4*)(lds + r * OSTR + h * 128 + c8 * 16);
            const unsigned int* w = (const unsigned int*)&v;
#pragma unroll
            for (int q = 0; q < 4; ++q) {
                const unsigned int a = key_of(w[q] & 0xFFFFu), b = key_of(w[q] >> 16);
                const unsigned int m = a > b ? a : b;
                mk = m > mk ? m : mk;
            }
        }
        const unsigned int o = (unsigned int)__shfl_xor((int)mk, 1);
        mk = o > mk ? o : mk;
        if (h == 0) tmax[(size_t)(n0 >> 7) * Q + m0 + r] = (unsigned short)mk;
    }

    // epilogue pass 2: coalesced 16B stores
#pragma unroll
    for (int p = 0; p < 8; ++p) {
        const int idx = p * 256 + t;
        const int r = idx >> 4, c = idx & 15;
        *(uint4*)(out + (size_t)(m0 + r) * NN + n0 + c * 8) = *(const uint4*)(lds + r * OSTR + c * 16);
    }
}

// ---------------------------------------------------------------- row select via tile-max pruning
// One block per row. tau_lb = rank-33 of the 128 tile-max keys (33 tiles with
// max >= tau_lb each hold >=1 element >= tau_lb => tau_lb <= tau*; any element
// >= tau_lb lies in a tile with max >= tau_lb). Thread t owns tile t>>1 half
// t&1 (64 cols); only ~35/128 tiles are loaded+scanned. Emit + r8-validated
// exact merge + predicated writeback (inactive threads write pure fill).
__global__ __launch_bounds__(256) void rowsel_kernel(unsigned short* __restrict__ out,
                                                     const unsigned short* __restrict__ tmax) {
    const int row = blockIdx.x;
    unsigned short* rowp = out + (size_t)row * NN;
    const int t = threadIdx.x;
    const int lane = t & 63;
    const int wave = t >> 6;

    __shared__ unsigned short s_tm[128];
    __shared__ unsigned int   s_cand[4][CAND];   // (key<<16) | col
    __shared__ int            s_cnum[4];
    __shared__ unsigned int   s_tau;
    __shared__ int            s_nsel;
    __shared__ int            s_selcol[40];

    if (t < 128) s_tm[t] = tmax[(size_t)t * Q + row];
    __syncthreads();                         // barrier 1

    // tau_lb redundantly per wave (r12's validated distributed pattern)
    const unsigned int ka = s_tm[2 * lane], kb = s_tm[2 * lane + 1];
    unsigned int taulb = 0;
#pragma unroll
    for (int b = 15; b >= 0; --b) {
        const unsigned int tc = taulb | (1u << b);
        int c = (int)(ka >= tc) + (int)(kb >= tc);
#pragma unroll
        for (int off = 1; off < 64; off <<= 1) c += __shfl_xor(c, off);
        if (c >= KSEL) taulb = tc;           // wave-uniform
    }

    const int tile = t >> 1, h = t & 1;
    const int cbase = tile * 128 + h * 64;   // my 64-col range
    const bool active = s_tm[tile] >= taulb;

    uint4 d[8];
    int cge = 0;
    if (active) {                            // load + key-transform + count
        const uint4* tp = (const uint4*)(rowp + cbase);
#pragma unroll
        for (int j = 0; j < 8; ++j) d[j] = tp[j];
#pragma unroll
        for (int j = 0; j < 8; ++j) {
            unsigned int* w = (unsigned int*)&d[j];
#pragma unroll
            for (int q = 0; q < 4; ++q) {
                w[q] = key_of(w[q] & 0xFFFFu) | (key_of(w[q] >> 16) << 16);
                cge += (int)((w[q] & 0xFFFFu) >= taulb) + (int)((w[q] >> 16) >= taulb);
            }
        }
    }
    int p = cge;
#pragma unroll
    for (int off = 1; off < 64; off <<= 1) {
        const int v = __shfl_up(p, off);
        if (lane >= off) p += v;
    }
    int slot = p - cge;
    if (cge) {
#pragma unroll
        for (int j = 0; j < 8; ++j) {
            const unsigned int* w = (const unsigned int*)&d[j];
#pragma unroll
            for (int q = 0; q < 4; ++q) {
#pragma unroll
                for (int hh = 0; hh < 2; ++hh) {
                    const unsigned int k = hh ? (w[q] >> 16) : (w[q] & 0xFFFFu);
                    if (k >= taulb) {
                        if (slot < CAND)
                            s_cand[wave][slot] = (k << 16) | (unsigned int)(cbase + j * 8 + q * 2 + hh);
                        ++slot;
                    }
                }
            }
        }
    }
    if (lane == 63) s_cnum[wave] = (p < CAND) ? p : CAND;
    __syncthreads();                         // barrier 2

    // wave-0 exact merge (r8-validated; low 16 bits now = col)
    if (wave == 0) {
        const int n0c = s_cnum[0], n1c = s_cnum[1], n2c = s_cnum[2], n3c = s_cnum[3];
        const int M = n0c + n1c + n2c + n3c;
        unsigned int e[6]; bool val[6];
#pragma unroll
        for (int s = 0; s < 6; ++s) {
            const int i = lane + 64 * s;
            val[s] = (i < M);
            unsigned int v = 0;
            if (val[s]) {
                int ii = i;
                if (ii < n0c) v = s_cand[0][ii];
                else { ii -= n0c;
                    if (ii < n1c) v = s_cand[1][ii];
                    else { ii -= n1c;
                        if (ii < n2c) v = s_cand[2][ii];
                        else v = s_cand[3][ii - n2c]; } }
            }
            e[s] = v;
        }
        unsigned int T = 0;
#pragma unroll
        for (int b = 15; b >= 0; --b) {
            const unsigned int tc = T | (1u << b);
            int c = 0;
#pragma unroll
            for (int s = 0; s < 6; ++s) c += (int)(val[s] && (e[s] >> 16) >= tc);
#pragma unroll
            for (int off = 1; off < 64; off <<= 1) c += __shfl_xor(c, off);
            if (c >= KSEL) T = tc;
        }
        int cgt = 0;
#pragma unroll
        for (int s = 0; s < 6; ++s) cgt += (int)(val[s] && (e[s] >> 16) > T);
#pragma unroll
        for (int off = 1; off < 64; off <<= 1) cgt += __shfl_xor(cgt, off);
        int tneed = KSEL - cgt;
        if (tneed < 0) tneed = 0;
        if (tneed > 40) tneed = 40;

        bool taken[6] = {false, false, false, false, false, false};
        for (int k = 0; k < tneed; ++k) {
            int m = 0x7fffffff;
#pragma unroll
            for (int s = 0; s < 6; ++s)
                if (val[s] && !taken[s] && (e[s] >> 16) == T) {
                    const int g = (int)(e[s] & 0xFFFFu);
                    if (g < m) m = g;
                }
#pragma unroll
            for (int off = 1; off < 64; off <<= 1) {
                const int o = __shfl_xor(m, off);
                if (o < m) m = o;
            }
            if (m == 0x7fffffff) { if (lane == 0) s_selcol[k] = -1; continue; }
#pragma unroll
            for (int s = 0; s < 6; ++s)
                if (val[s] && !taken[s] && (e[s] >> 16) == T && (int)(e[s] & 0xFFFFu) == m) {
                    taken[s] = true;          // unique col -> exactly one lane
                    s_selcol[k] = m;
                }
        }
        if (lane == 0) { s_tau = T; s_nsel = tneed; }
    }
    __syncthreads();                         // barrier 3

    // writeback: active threads keep (key > T)-selected + tie-cols; others fill
    const unsigned int T = s_tau;
    const int nsel = s_nsel;
    uint4* wp4 = (uint4*)(rowp + cbase);
    if (active) {
        unsigned long long cons = 0ull;
        for (int k = 0; k < nsel; ++k) {
            const int c = s_selcol[k] - cbase;
            if (c >= 0 && c < 64) cons |= 1ull << c;
        }
#pragma unroll
        for (int j = 0; j < 8; ++j) {
            const unsigned int* w = (const unsigned int*)&d[j];
            uint4 o;
            unsigned int* ow = (unsigned int*)&o;
#pragma unroll
            for (int q = 0; q < 4; ++q) {
                const unsigned int klo = w[q] & 0xFFFFu, khi = w[q] >> 16;
                const int ord = j * 8 + q * 2;
                const bool sl = (klo > T) || ((cons >> ord) & 1ull);
                const bool sh = (khi > T) || ((cons >> (ord + 1)) & 1ull);
                const unsigned int lo = sl ? patch16(inv_key(klo)) : 0xFBFFu;
                const unsigned int hi = sh ? patch16(inv_key(khi)) : 0xFBFFu;
                ow[q] = lo | (hi << 16);
            }
            wp4[j] = o;
        }
    } else {
        const uint4 fv = {0xFBFFFBFFu, 0xFBFFFBFFu, 0xFBFFFBFFu, 0xFBFFFBFFu};
#pragma unroll
        for (int j = 0; j < 8; ++j) wp4[j] = fv;
    }
}

// ---------------------------------------------------------------- top-33 fallback (r12, used only if ws too small)
__global__ __launch_bounds__(256) void topk_kernel(unsigned short* __restrict__ out) {
    const int row = blockIdx.x;
    unsigned short* rowp = out + (size_t)row * NN;
    const int t = threadIdx.x;
    const int lane = t & 63;
    const int wave = t >> 6;

    __shared__ unsigned short s_tmax[256];
    __shared__ unsigned int   s_cand[4][CAND];
    __shared__ int            s_cnum[4];
    __shared__ unsigned int   s_tau;
    __shared__ int            s_nsel;
    __shared__ int            s_selgi[40];

    uint4 d[8];
    const uint4* rp4 = (const uint4*)rowp;
#pragma unroll
    for (int j = 0; j < 8; ++j) d[j] = rp4[j * 256 + t];
#pragma unroll
    for (int j = 0; j < 8; ++j) {
        unsigned int* w = (unsigned int*)&d[j];
#pragma unroll
        for (int q = 0; q < 4; ++q)
            w[q] = key_of(w[q] & 0xFFFFu) | (key_of(w[q] >> 16) << 16);
    }
    unsigned int tm = 0;
#pragma unroll
    for (int j = 0; j < 8; ++j) {
        const unsigned int* w = (const unsigned int*)&d[j];
#pragma unroll
        for (int q = 0; q < 4; ++q) {
            const unsigned int a = w[q] & 0xFFFFu, b = w[q] >> 16;
            const unsigned int m = a > b ? a : b;
            tm = m > tm ? m : tm;
        }
    }
    s_tmax[t] = (unsigned short)tm;
    __syncthreads();

    unsigned int k0 = s_tmax[lane],       k1 = s_tmax[lane + 64],
                 k2 = s_tmax[lane + 128], k3 = s_tmax[lane + 192];
    unsigned int taulb = 0;
#pragma unroll
    for (int b = 15; b >= 0; --b) {
        const unsigned int tc = taulb | (1u << b);
        int c = (int)(k0 >= tc) + (int)(k1 >= tc) + (int)(k2 >= tc) + (int)(k3 >= tc);
#pragma unroll
        for (int off = 1; off < 64; off <<= 1) c += __shfl_xor(c, off);
        if (c >= KSEL) taulb = tc;
    }
    int cge = 0;
#pragma unroll
    for (int j = 0; j < 8; ++j) {
        const unsigned int* w = (const unsigned int*)&d[j];
#pragma unroll
        for (int q = 0; q < 4; ++q)
            cge += (int)((w[q] & 0xFFFFu) >= taulb) + (int)((w[q] >> 16) >= taulb);
    }
    int p = cge;
#pragma unroll
    for (int off = 1; off < 64; off <<= 1) {
        const int v = __shfl_up(p, off);
        if (lane >= off) p += v;
    }
    int slot = p - cge;
    if (cge) {
#pragma unroll
        for (int j = 0; j < 8; ++j) {
            const unsigned int* w = (const unsigned int*)&d[j];
#pragma unroll
            for (int q = 0; q < 4; ++q) {
#pragma unroll
                for (int h = 0; h < 2; ++h) {
                    const unsigned int k = h ? (w[q] >> 16) : (w[q] & 0xFFFFu);
                    if (k >= taulb) {
                        if (slot < CAND)
                            s_cand[wave][slot] = (k << 16) | (unsigned int)((j << 11) + (t << 3) + q * 2 + h);
                        ++slot;
                    }
                }
            }
        }
    }
    if (lane == 63) s_cnum[wave] = (p < CAND) ? p : CAND;
    __syncthreads();

    if (wave == 0) {
        const int n0c = s_cnum[0], n1c = s_cnum[1], n2c = s_cnum[2], n3c = s_cnum[3];
        const int M = n0c + n1c + n2c + n3c;
        unsigned int e[6]; bool val[6];
#pragma unroll
        for (int s = 0; s < 6; ++s) {
            const int i = lane + 64 * s;
            val[s] = (i < M);
            unsigned int v = 0;
            if (val[s]) {
                int ii = i;
                if (ii < n0c) v = s_cand[0][ii];
                else { ii -= n0c;
                    if (ii < n1c) v = s_cand[1][ii];
                    else { ii -= n1c;
                        if (ii < n2c) v = s_cand[2][ii];
                        else v = s_cand[3][ii - n2c]; } }
            }
            e[s] = v;
        }
        unsigned int T = 0;
#pragma unroll
        for (int b = 15; b >= 0; --b) {
            const unsigned int tc = T | (1u << b);
            int c = 0;
#pragma unroll
            for (int s = 0; s < 6; ++s) c += (int)(val[s] && (e[s] >> 16) >= tc);
#pragma unroll
            for (int off = 1; off < 64; off <<= 1) c += __shfl_xor(c, off);
            if (c >= KSEL) T = tc;
        }
        int cgt = 0;
#pragma unroll
        for (int s = 0; s < 6; ++s) cgt += (int)(val[s] && (e[s] >> 16) > T);
#pragma unroll
        for (int off = 1; off < 64; off <<= 1) cgt += __shfl_xor(cgt, off);
        int tneed = KSEL - cgt;
        if (tneed < 0) tneed = 0;
        if (tneed > 40) tneed = 40;
        bool taken[6] = {false, false, false, false, false, false};
        for (int k = 0; k < tneed; ++k) {
            int m = 0x7fffffff;
#pragma unroll
            for (int s = 0; s < 6; ++s)
                if (val[s] && !taken[s] && (e[s] >> 16) == T) {
                    const int g = (int)(e[s] & 0xFFFFu);
                    if (g < m) m = g;
                }
#pragma unroll
            for (int off = 1; off < 64; off <<= 1) {
                const int o = __shfl_xor(m, off);
                if (o < m) m = o;
            }
            if (m == 0x7fffffff) { if (lane == 0) s_selgi[k] = -1; continue; }
#pragma unroll
            for (int s = 0; s < 6; ++s)
                if (val[s] && !taken[s] && (e[s] >> 16) == T && (int)(e[s] & 0xFFFFu) == m) {
                    taken[s] = true;
                    s_selgi[k] = m;
                }
        }
        if (lane == 0) { s_tau = T; s_nsel = tneed; }
    }
    __syncthreads();

    const unsigned int T = s_tau;
    const int nsel = s_nsel;
    unsigned long long cons = 0ull;
    for (int k = 0; k < nsel; ++k) {
        const int g = s_selgi[k];
        if (g >= 0 && ((g >> 3) & 255) == t) cons |= 1ull << (((g >> 11) << 3) | (g & 7));
    }
    uint4* wp4 = (uint4*)rowp;
#pragma unroll
    for (int j = 0; j < 8; ++j) {
        const unsigned int* w = (const unsigned int*)&d[j];
        uint4 o;
        unsigned int* ow = (unsigned int*)&o;
#pragma unroll
        for (int q = 0; q < 4; ++q) {
            const unsigned int klo = w[q] & 0xFFFFu, khi = w[q] >> 16;
            const int ord = j * 8 + q * 2;
            const bool sl = (klo > T) || ((cons >> ord) & 1ull);
            const bool sh = (khi > T) || ((cons >> (ord + 1)) & 1ull);
            const unsigned int lo = sl ? patch16(inv_key(klo)) : 0xFBFFu;
            const unsigned int hi = sh ? patch16(inv_key(khi)) : 0xFBFFu;
            ow[q] = lo | (hi << 16);
        }
        wp4[j * 256 + t] = o;
    }
}

// ---------------------------------------------------------------- launch
extern "C" void kernel_launch(void* const* d_in, const int* in_sizes, int n_in,
                              void* d_out, int out_size, void* d_ws, size_t ws_size,
                              hipStream_t stream) {
    const unsigned short* x  = (const unsigned short*)d_in[0];   // [4096 x 256] f16
    const unsigned short* xn = (const unsigned short*)d_in[1];   // [16384 x 256] f16
    unsigned short* out = (unsigned short*)d_out;                // [4096 x 16384] f16
    float* ws = (float*)d_ws;
    unsigned short* tmax = (unsigned short*)((char*)d_ws + WS_NORMS);

    if (ws_size >= WS_FULL) {
        norms_kernel<<<(Q + NN) / 64, 256, 0, stream>>>(x, xn, ws);
        gemm_sim_kernel<true, true><<<dim3(NN / 128, Q / 128), 256, 0, stream>>>(x, xn, ws, tmax, out);
        rowsel_kernel<<<Q, 256, 0, stream>>>(out, tmax);
    } else if (ws_size >= WS_NORMS) {
        norms_kernel<<<(Q + NN) / 64, 256, 0, stream>>>(x, xn, ws);
        gemm_sim_kernel<true, false><<<dim3(NN / 128, Q / 128), 256, 0, stream>>>(x, xn, ws, nullptr, out);
        topk_kernel<<<Q, 256, 0, stream>>>(out);
    } else {
        gemm_sim_kernel<false, false><<<dim3(NN / 128, Q / 128), 256, 0, stream>>>(x, xn, nullptr, nullptr, out);
        topk_kernel<<<Q, 256, 0, stream>>>(out);
    }
}

// Round 14
// 403.934 us; speedup vs baseline: 2.2601x; 1.0384x over previous
//
#include <hip/hip_runtime.h>
#include <hip/hip_fp16.h>
#include <math.h>

#define Q    4096
#define NN   16384
#define DD   256
#define KSEL 33
#define CAND 96    // per-wave candidate cap
#define OSTR 264   // epilogue LDS row stride bytes: 256 B data + 8 B pad
#define TM_BYTES (128 * Q * 2)                 // tilemax[tileN][row] u16 keys
#define WS_NORMS ((size_t)(Q + NN) * 4)
#define WS_FULL  (WS_NORMS + TM_BYTES)

typedef __attribute__((ext_vector_type(8))) _Float16 half8;
typedef __attribute__((ext_vector_type(4))) float    floatx4;

__device__ __forceinline__ float h2f(unsigned short u) {
    union { unsigned short s; _Float16 h; } c; c.s = u;
    return (float)c.h;
}
// f32 -> f16 raw bits, guaranteed FINITE pattern (exp field != 0x1F)
__device__ __forceinline__ unsigned short f2h_finite(float v) {
    v = fminf(fmaxf(v, -65504.0f), 65504.0f);       // IEEE fmax/fmin: NaN -> -65504
    union { _Float16 h; unsigned short s; } c; c.h = (_Float16)v;
    unsigned short u = c.s;
    if ((u & 0x7C00u) == 0x7C00u) u = (u & 0x8000u) ? 0xFBFFu : 0x7BFFu;
    return u;
}
__device__ __forceinline__ unsigned int patch16(unsigned int u) {
    if ((u & 0x7C00u) == 0x7C00u) u = (u & 0x8000u) ? 0xFBFFu : 0x7BFFu;
    return u;
}
// monotone f16-bits -> sortable u16 (larger float => larger key); involutive pair
__device__ __forceinline__ unsigned int key_of(unsigned int u) {
    return (u & 0x8000u) ? (u ^ 0xFFFFu) : (u | 0x8000u);
}
__device__ __forceinline__ unsigned int inv_key(unsigned int k) {
    return (k & 0x8000u) ? (k ^ 0x8000u) : (~k & 0xFFFFu);
}
// async 16B global -> LDS (m97). Dest = wave-uniform base + lane*16 [m104].
__device__ __forceinline__ void gload_lds16(const unsigned short* g, char* l) {
    __builtin_amdgcn_global_load_lds(
        (const __attribute__((address_space(1))) void*)g,
        (__attribute__((address_space(3))) void*)l, 16, 0, 0);
}

// ---------------------------------------------------------------- row norms -> ws
__global__ __launch_bounds__(256) void norms_kernel(const unsigned short* __restrict__ x,
                                                    const unsigned short* __restrict__ xn,
                                                    float* __restrict__ ws) {
    const int t = threadIdx.x;
    const int g = blockIdx.x * 64 + (t >> 2);
    const int sub = t & 3;
    const unsigned short* src = (g < Q) ? (x + (size_t)g * DD)
                                        : (xn + (size_t)(g - Q) * DD);
    float s = 0.f;
#pragma unroll
    for (int it = 0; it < 8; ++it) {
        const uint4 v = *(const uint4*)(src + (it * 4 + sub) * 8);
        const unsigned int* w = (const unsigned int*)&v;
#pragma unroll
        for (int q = 0; q < 4; ++q) {
            const float a = h2f(w[q] & 0xFFFF), b = h2f(w[q] >> 16);
            s = fmaf(a, a, s); s = fmaf(b, b, s);
        }
    }
    s += __shfl_xor(s, 1);
    s += __shfl_xor(s, 2);
    if (sub == 0) ws[g] = s;
}

// ---------------------------------------------------------------- sim GEMM (MFMA f16) — r13 verbatim
template <bool WS, bool TM>
__global__ __launch_bounds__(256) void gemm_sim_kernel(const unsigned short* __restrict__ A,
                                                       const unsigned short* __restrict__ B,
                                                       const float* __restrict__ ws,
                                                       unsigned short* __restrict__ tmax,
                                                       unsigned short* __restrict__ out) {
    __shared__ char  lds[128 * OSTR];
    __shared__ float s_x2[128];
    __shared__ float s_y2[128];
    char* ldsA = lds;
    char* ldsB = lds + 8192;

    const int t    = threadIdx.x;
    const int m0   = blockIdx.y * 128;
    const int n0   = blockIdx.x * 128;
    const int wave = t >> 6;
    const int lane = t & 63;
    const int wm   = (wave & 1) << 6;
    const int wn   = (wave >> 1) << 6;
    const int l15  = lane & 15;
    const int quad = lane >> 4;
    const int r0   = t >> 2;
    const int qq   = t & 3;

    if (WS) {
        if (t < 128) s_x2[t] = ws[m0 + t];
        else         s_y2[t - 128] = ws[Q + n0 + (t - 128)];
    }

    floatx4 acc[4][4];
#pragma unroll
    for (int i = 0; i < 4; ++i)
#pragma unroll
        for (int j = 0; j < 4; ++j) {
            acc[i][j][0] = 0.f; acc[i][j][1] = 0.f; acc[i][j][2] = 0.f; acc[i][j][3] = 0.f;
        }
    float pa[2] = {0.f, 0.f}, pb[2] = {0.f, 0.f};

    for (int k0 = 0; k0 < DD; k0 += 32) {
        if (WS) {
            __syncthreads();
#pragma unroll
            for (int j = 0; j < 2; ++j) {
                gload_lds16(A + (size_t)(m0 + r0 + 64 * j) * DD + k0 + qq * 8,
                            ldsA + j * 4096 + t * 16);
                gload_lds16(B + (size_t)(n0 + r0 + 64 * j) * DD + k0 + qq * 8,
                            ldsB + j * 4096 + t * 16);
            }
        } else {
            float4 ar[2], br[2];
#pragma unroll
            for (int j = 0; j < 2; ++j) {
                const int r = r0 + (j << 6);
                ar[j] = *(const float4*)(A + (size_t)(m0 + r) * DD + k0 + qq * 8);
                br[j] = *(const float4*)(B + (size_t)(n0 + r) * DD + k0 + qq * 8);
                const unsigned short* ua = (const unsigned short*)&ar[j];
                const unsigned short* ub = (const unsigned short*)&br[j];
#pragma unroll
                for (int e = 0; e < 8; ++e) {
                    const float fa = h2f(ua[e]); pa[j] = fmaf(fa, fa, pa[j]);
                    const float fb = h2f(ub[e]); pb[j] = fmaf(fb, fb, pb[j]);
                }
            }
            __syncthreads();
#pragma unroll
            for (int j = 0; j < 2; ++j) {
                const int r = r0 + (j << 6);
                *(float4*)(ldsA + r * 64 + qq * 16) = ar[j];
                *(float4*)(ldsB + r * 64 + qq * 16) = br[j];
            }
        }
        __syncthreads();
        half8 af[4], bg[4];
#pragma unroll
        for (int s = 0; s < 4; ++s) {
            af[s] = *(const half8*)(ldsA + (wm + s * 16 + l15) * 64 + quad * 16);
            bg[s] = *(const half8*)(ldsB + (wn + s * 16 + l15) * 64 + quad * 16);
        }
#pragma unroll
        for (int si = 0; si < 4; ++si)
#pragma unroll
            for (int sj = 0; sj < 4; ++sj)
                acc[si][sj] = __builtin_amdgcn_mfma_f32_16x16x32_f16(af[si], bg[sj], acc[si][sj], 0, 0, 0);
    }

    if (!WS) {
#pragma unroll
        for (int j = 0; j < 2; ++j) {
            pa[j] += __shfl_xor(pa[j], 1); pa[j] += __shfl_xor(pa[j], 2);
            pb[j] += __shfl_xor(pb[j], 1); pb[j] += __shfl_xor(pb[j], 2);
        }
        if (qq == 0) {
            s_x2[r0] = pa[0]; s_x2[64 + r0] = pa[1];
            s_y2[r0] = pb[0]; s_y2[64 + r0] = pb[1];
        }
    }
    __syncthreads();

#pragma unroll
    for (int si = 0; si < 4; ++si) {
#pragma unroll
        for (int r = 0; r < 4; ++r) {
            const int lrow = wm + si * 16 + quad * 4 + r;
            const float xv = s_x2[lrow];
#pragma unroll
            for (int sj = 0; sj < 4; ++sj) {
                const int lcol = wn + sj * 16 + l15;
                float d2 = fmaxf(xv + s_y2[lcol] - 2.0f * acc[si][sj][r], 0.0f);
                d2 = fminf(d2, 1e9f);
                *(unsigned short*)(lds + lrow * OSTR + lcol * 2) = f2h_finite(-sqrtf(d2));
            }
        }
    }
    __syncthreads();

    // tilemax: thread pair (2r, 2r+1) scans LDS row r halves, combines via shfl
    if (TM) {
        const int r = t >> 1, h = t & 1;
        unsigned int mk = 0;
#pragma unroll
        for (int c8 = 0; c8 < 8; ++c8) {
            const uint4 v = *(const uint4*)(lds + r * OSTR + h * 128 + c8 * 16);
            const unsigned int* w = (const unsigned int*)&v;
#pragma unroll
            for (int q = 0; q < 4; ++q) {
                const unsigned int a = key_of(w[q] & 0xFFFFu), b = key_of(w[q] >> 16);
                const unsigned int m = a > b ? a : b;
                mk = m > mk ? m : mk;
            }
        }
        const unsigned int o = (unsigned int)__shfl_xor((int)mk, 1);
        mk = o > mk ? o : mk;
        if (h == 0) tmax[(size_t)(n0 >> 7) * Q + m0 + r] = (unsigned short)mk;
    }

#pragma unroll
    for (int p = 0; p < 8; ++p) {
        const int idx = p * 256 + t;
        const int r = idx >> 4, c = idx & 15;
        *(uint4*)(out + (size_t)(m0 + r) * NN + n0 + c * 8) = *(const uint4*)(lds + r * OSTR + c * 16);
    }
}

// ---------------------------------------------------------------- row select v2: tile-max pruning + coalesced fill/scatter
// Scan ownership (tile t>>1, half t&1) != store ownership (interleaved j*256+t):
// r13's tile-owned stores caused 70 MB write-allocate FETCH + 70 MB extra WRITE
// (16B/128B-line density). v2: merge builds the full 33-entry selected list,
// then ALL threads fill coalesced and 33 threads scatter (r5-validated order:
// __syncthreads drains vmcnt before barrier).
__global__ __launch_bounds__(256) void rowsel_kernel(unsigned short* __restrict__ out,
                                                     const unsigned short* __restrict__ tmax) {
    const int row = blockIdx.x;
    unsigned short* rowp = out + (size_t)row * NN;
    const int t = threadIdx.x;
    const int lane = t & 63;
    const int wave = t >> 6;

    __shared__ unsigned short s_tm[128];
    __shared__ unsigned int   s_cand[4][CAND];   // (key<<16) | col
    __shared__ int            s_cnum[4];
    __shared__ unsigned int   s_sel[KSEL + 8];   // (key<<16) | col, exactly KSEL valid

    if (t < 128) s_tm[t] = tmax[(size_t)t * Q + row];
    if (t >= 128 && t < 128 + KSEL + 8) s_sel[t - 128] = 0xFFFFFFFFu;  // col sentinel >= NN
    __syncthreads();                         // barrier 1

    // tau_lb redundantly per wave (r12/r13-validated distributed pattern)
    const unsigned int ka = s_tm[2 * lane], kb = s_tm[2 * lane + 1];
    unsigned int taulb = 0;
#pragma unroll
    for (int b = 15; b >= 0; --b) {
        const unsigned int tc = taulb | (1u << b);
        int c = (int)(ka >= tc) + (int)(kb >= tc);
#pragma unroll
        for (int off = 1; off < 64; off <<= 1) c += __shfl_xor(c, off);
        if (c >= KSEL) taulb = tc;           // wave-uniform
    }

    const int tile = t >> 1, h = t & 1;
    const int cbase = tile * 128 + h * 64;   // my 64-col scan range
    const bool active = s_tm[tile] >= taulb;

    uint4 d[8];
    int cge = 0;
    if (active) {                            // load + key-transform + count
        const uint4* tp = (const uint4*)(rowp + cbase);
#pragma unroll
        for (int j = 0; j < 8; ++j) d[j] = tp[j];
#pragma unroll
        for (int j = 0; j < 8; ++j) {
            unsigned int* w = (unsigned int*)&d[j];
#pragma unroll
            for (int q = 0; q < 4; ++q) {
                w[q] = key_of(w[q] & 0xFFFFu) | (key_of(w[q] >> 16) << 16);
                cge += (int)((w[q] & 0xFFFFu) >= taulb) + (int)((w[q] >> 16) >= taulb);
            }
        }
    }
    int p = cge;
#pragma unroll
    for (int off = 1; off < 64; off <<= 1) {
        const int v = __shfl_up(p, off);
        if (lane >= off) p += v;
    }
    int slot = p - cge;
    if (cge) {
#pragma unroll
        for (int j = 0; j < 8; ++j) {
            const unsigned int* w = (const unsigned int*)&d[j];
#pragma unroll
            for (int q = 0; q < 4; ++q) {
#pragma unroll
                for (int hh = 0; hh < 2; ++hh) {
                    const unsigned int k = hh ? (w[q] >> 16) : (w[q] & 0xFFFFu);
                    if (k >= taulb) {
                        if (slot < CAND)
                            s_cand[wave][slot] = (k << 16) | (unsigned int)(cbase + j * 8 + q * 2 + hh);
                        ++slot;
                    }
                }
            }
        }
    }
    if (lane == 63) s_cnum[wave] = (p < CAND) ? p : CAND;
    __syncthreads();                         // barrier 2

    // wave-0 exact merge -> full 33-entry selected list in s_sel
    if (wave == 0) {
        const int n0c = s_cnum[0], n1c = s_cnum[1], n2c = s_cnum[2], n3c = s_cnum[3];
        const int M = n0c + n1c + n2c + n3c;
        unsigned int e[6]; bool val[6];
#pragma unroll
        for (int s = 0; s < 6; ++s) {
            const int i = lane + 64 * s;
            val[s] = (i < M);
            unsigned int v = 0;
            if (val[s]) {
                int ii = i;
                if (ii < n0c) v = s_cand[0][ii];
                else { ii -= n0c;
                    if (ii < n1c) v = s_cand[1][ii];
                    else { ii -= n1c;
                        if (ii < n2c) v = s_cand[2][ii];
                        else v = s_cand[3][ii - n2c]; } }
            }
            e[s] = v;
        }
        unsigned int T = 0;
#pragma unroll
        for (int b = 15; b >= 0; --b) {
            const unsigned int tc = T | (1u << b);
            int c = 0;
#pragma unroll
            for (int s = 0; s < 6; ++s) c += (int)(val[s] && (e[s] >> 16) >= tc);
#pragma unroll
            for (int off = 1; off < 64; off <<= 1) c += __shfl_xor(c, off);
            if (c >= KSEL) T = tc;
        }
        // compact all key > T into s_sel[0..cgt)
        int myc = 0;
#pragma unroll
        for (int s = 0; s < 6; ++s) myc += (int)(val[s] && (e[s] >> 16) > T);
        int pf = myc;
#pragma unroll
        for (int off = 1; off < 64; off <<= 1) {
            const int v = __shfl_up(pf, off);
            if (lane >= off) pf += v;
        }
        int sl = pf - myc;
#pragma unroll
        for (int s = 0; s < 6; ++s)
            if (val[s] && (e[s] >> 16) > T) s_sel[sl++] = e[s];
        int cgt = (int)__shfl(pf, 63);       // total > T (< KSEL by maximality of T)
        int tneed = KSEL - cgt;
        if (tneed < 0) tneed = 0;

        // append tneed lowest-col ties (key == T) via iterative butterfly-min
        bool taken[6] = {false, false, false, false, false, false};
        for (int k = 0; k < tneed; ++k) {
            int m = 0x7fffffff;
#pragma unroll
            for (int s = 0; s < 6; ++s)
                if (val[s] && !taken[s] && (e[s] >> 16) == T) {
                    const int g = (int)(e[s] & 0xFFFFu);
                    if (g < m) m = g;
                }
#pragma unroll
            for (int off = 1; off < 64; off <<= 1) {
                const int o = __shfl_xor(m, off);
                if (o < m) m = o;
            }
            if (m == 0x7fffffff) break;      // fewer ties than needed (cannot happen: M>=KSEL)
#pragma unroll
            for (int s = 0; s < 6; ++s)
                if (val[s] && !taken[s] && (e[s] >> 16) == T && (int)(e[s] & 0xFFFFu) == m) {
                    taken[s] = true;          // unique col -> exactly one lane writes
                    s_sel[cgt + k] = e[s];
                }
        }
    }
    __syncthreads();                         // barrier 3

    // coalesced fill of the whole row (full lines, no write-allocate fetch)
    const uint4 fv = {0xFBFFFBFFu, 0xFBFFFBFFu, 0xFBFFFBFFu, 0xFBFFFBFFu};
    uint4* wp4 = (uint4*)rowp;
#pragma unroll
    for (int j = 0; j < 8; ++j) wp4[j * 256 + t] = fv;
    __syncthreads();                         // drains vmcnt -> fill ordered before scatter

    // scatter the 33 selected values (patched-finite)
    if (t < KSEL) {
        const unsigned int e = s_sel[t];
        const unsigned int col = e & 0xFFFFu;
        if (col < NN) rowp[col] = (unsigned short)patch16(inv_key(e >> 16));
    }
}

// ---------------------------------------------------------------- top-33 fallback (r12, used only if ws too small)
__global__ __launch_bounds__(256) void topk_kernel(unsigned short* __restrict__ out) {
    const int row = blockIdx.x;
    unsigned short* rowp = out + (size_t)row * NN;
    const int t = threadIdx.x;
    const int lane = t & 63;
    const int wave = t >> 6;

    __shared__ unsigned short s_tmax[256];
    __shared__ unsigned int   s_cand[4][CAND];
    __shared__ int            s_cnum[4];
    __shared__ unsigned int   s_tau;
    __shared__ int            s_nsel;
    __shared__ int            s_selgi[40];

    uint4 d[8];
    const uint4* rp4 = (const uint4*)rowp;
#pragma unroll
    for (int j = 0; j < 8; ++j) d[j] = rp4[j * 256 + t];
#pragma unroll
    for (int j = 0; j < 8; ++j) {
        unsigned int* w = (unsigned int*)&d[j];
#pragma unroll
        for (int q = 0; q < 4; ++q)
            w[q] = key_of(w[q] & 0xFFFFu) | (key_of(w[q] >> 16) << 16);
    }
    unsigned int tm = 0;
#pragma unroll
    for (int j = 0; j < 8; ++j) {
        const unsigned int* w = (const unsigned int*)&d[j];
#pragma unroll
        for (int q = 0; q < 4; ++q) {
            const unsigned int a = w[q] & 0xFFFFu, b = w[q] >> 16;
            const unsigned int m = a > b ? a : b;
            tm = m > tm ? m : tm;
        }
    }
    s_tmax[t] = (unsigned short)tm;
    __syncthreads();

    unsigned int k0 = s_tmax[lane],       k1 = s_tmax[lane + 64],
                 k2 = s_tmax[lane + 128], k3 = s_tmax[lane + 192];
    unsigned int taulb = 0;
#pragma unroll
    for (int b = 15; b >= 0; --b) {
        const unsigned int tc = taulb | (1u << b);
        int c = (int)(k0 >= tc) + (int)(k1 >= tc) + (int)(k2 >= tc) + (int)(k3 >= tc);
#pragma unroll
        for (int off = 1; off < 64; off <<= 1) c += __shfl_xor(c, off);
        if (c >= KSEL) taulb = tc;
    }
    int cge = 0;
#pragma unroll
    for (int j = 0; j < 8; ++j) {
        const unsigned int* w = (const unsigned int*)&d[j];
#pragma unroll
        for (int q = 0; q < 4; ++q)
            cge += (int)((w[q] & 0xFFFFu) >= taulb) + (int)((w[q] >> 16) >= taulb);
    }
    int p = cge;
#pragma unroll
    for (int off = 1; off < 64; off <<= 1) {
        const int v = __shfl_up(p, off);
        if (lane >= off) p += v;
    }
    int slot = p - cge;
    if (cge) {
#pragma unroll
        for (int j = 0; j < 8; ++j) {
            const unsigned int* w = (const unsigned int*)&d[j];
#pragma unroll
            for (int q = 0; q < 4; ++q) {
#pragma unroll
                for (int h = 0; h < 2; ++h) {
                    const unsigned int k = h ? (w[q] >> 16) : (w[q] & 0xFFFFu);
                    if (k >= taulb) {
                        if (slot < CAND)
                            s_cand[wave][slot] = (k << 16) | (unsigned int)((j << 11) + (t << 3) + q * 2 + h);
                        ++slot;
                    }
                }
            }
        }
    }
    if (lane == 63) s_cnum[wave] = (p < CAND) ? p : CAND;
    __syncthreads();

    if (wave == 0) {
        const int n0c = s_cnum[0], n1c = s_cnum[1], n2c = s_cnum[2], n3c = s_cnum[3];
        const int M = n0c + n1c + n2c + n3c;
        unsigned int e[6]; bool val[6];
#pragma unroll
        for (int s = 0; s < 6; ++s) {
            const int i = lane + 64 * s;
            val[s] = (i < M);
            unsigned int v = 0;
            if (val[s]) {
                int ii = i;
                if (ii < n0c) v = s_cand[0][ii];
                else { ii -= n0c;
                    if (ii < n1c) v = s_cand[1][ii];
                    else { ii -= n1c;
                        if (ii < n2c) v = s_cand[2][ii];
                        else v = s_cand[3][ii - n2c]; } }
            }
            e[s] = v;
        }
        unsigned int T = 0;
#pragma unroll
        for (int b = 15; b >= 0; --b) {
            const unsigned int tc = T | (1u << b);
            int c = 0;
#pragma unroll
            for (int s = 0; s < 6; ++s) c += (int)(val[s] && (e[s] >> 16) >= tc);
#pragma unroll
            for (int off = 1; off < 64; off <<= 1) c += __shfl_xor(c, off);
            if (c >= KSEL) T = tc;
        }
        int cgt = 0;
#pragma unroll
        for (int s = 0; s < 6; ++s) cgt += (int)(val[s] && (e[s] >> 16) > T);
#pragma unroll
        for (int off = 1; off < 64; off <<= 1) cgt += __shfl_xor(cgt, off);
        int tneed = KSEL - cgt;
        if (tneed < 0) tneed = 0;
        if (tneed > 40) tneed = 40;
        bool taken[6] = {false, false, false, false, false, false};
        for (int k = 0; k < tneed; ++k) {
            int m = 0x7fffffff;
#pragma unroll
            for (int s = 0; s < 6; ++s)
                if (val[s] && !taken[s] && (e[s] >> 16) == T) {
                    const int g = (int)(e[s] & 0xFFFFu);
                    if (g < m) m = g;
                }
#pragma unroll
            for (int off = 1; off < 64; off <<= 1) {
                const int o = __shfl_xor(m, off);
                if (o < m) m = o;
            }
            if (m == 0x7fffffff) { if (lane == 0) s_selgi[k] = -1; continue; }
#pragma unroll
            for (int s = 0; s < 6; ++s)
                if (val[s] && !taken[s] && (e[s] >> 16) == T && (int)(e[s] & 0xFFFFu) == m) {
                    taken[s] = true;
                    s_selgi[k] = m;
                }
        }
        if (lane == 0) { s_tau = T; s_nsel = tneed; }
    }
    __syncthreads();

    const unsigned int T = s_tau;
    const int nsel = s_nsel;
    unsigned long long cons = 0ull;
    for (int k = 0; k < nsel; ++k) {
        const int g = s_selgi[k];
        if (g >= 0 && ((g >> 3) & 255) == t) cons |= 1ull << (((g >> 11) << 3) | (g & 7));
    }
    uint4* wp4 = (uint4*)rowp;
#pragma unroll
    for (int j = 0; j < 8; ++j) {
        const unsigned int* w = (const unsigned int*)&d[j];
        uint4 o;
        unsigned int* ow = (unsigned int*)&o;
#pragma unroll
        for (int q = 0; q < 4; ++q) {
            const unsigned int klo = w[q] & 0xFFFFu, khi = w[q] >> 16;
            const int ord = j * 8 + q * 2;
            const bool sl = (klo > T) || ((cons >> ord) & 1ull);
            const bool sh = (khi > T) || ((cons >> (ord + 1)) & 1ull);
            const unsigned int lo = sl ? patch16(inv_key(klo)) : 0xFBFFu;
            const unsigned int hi = sh ? patch16(inv_key(khi)) : 0xFBFFu;
            ow[q] = lo | (hi << 16);
        }
        wp4[j * 256 + t] = o;
    }
}

// ---------------------------------------------------------------- launch
extern "C" void kernel_launch(void* const* d_in, const int* in_sizes, int n_in,
                              void* d_out, int out_size, void* d_ws, size_t ws_size,
                              hipStream_t stream) {
    const unsigned short* x  = (const unsigned short*)d_in[0];   // [4096 x 256] f16
    const unsigned short* xn = (const unsigned short*)d_in[1];   // [16384 x 256] f16
    unsigned short* out = (unsigned short*)d_out;                // [4096 x 16384] f16
    float* ws = (float*)d_ws;
    unsigned short* tmax = (unsigned short*)((char*)d_ws + WS_NORMS);

    if (ws_size >= WS_FULL) {
        norms_kernel<<<(Q + NN) / 64, 256, 0, stream>>>(x, xn, ws);
        gemm_sim_kernel<true, true><<<dim3(NN / 128, Q / 128), 256, 0, stream>>>(x, xn, ws, tmax, out);
        rowsel_kernel<<<Q, 256, 0, stream>>>(out, tmax);
    } else if (ws_size >= WS_NORMS) {
        norms_kernel<<<(Q + NN) / 64, 256, 0, stream>>>(x, xn, ws);
        gemm_sim_kernel<true, false><<<dim3(NN / 128, Q / 128), 256, 0, stream>>>(x, xn, ws, nullptr, out);
        topk_kernel<<<Q, 256, 0, stream>>>(out);
    } else {
        gemm_sim_kernel<false, false><<<dim3(NN / 128, Q / 128), 256, 0, stream>>>(x, xn, nullptr, nullptr, out);
        topk_kernel<<<Q, 256, 0, stream>>>(out);
    }
}